// Round 5
// baseline (338.212 us; speedup 1.0000x reference)
//
#include <hip/hip_runtime.h>
#include <math.h>

#define Bc 8
#define Nc 1024
#define Dc 1024
#define Hc 16
#define DHc 64
#define NEGINF -1e9f

typedef unsigned int  u32;
typedef unsigned short u16;
typedef unsigned long long u64;
typedef u16  u16x8 __attribute__((ext_vector_type(8)));
typedef u16  u16x4 __attribute__((ext_vector_type(4)));
typedef __bf16 bf16x8 __attribute__((ext_vector_type(8)));
typedef float f32x4 __attribute__((ext_vector_type(4)));

__device__ __forceinline__ u16 f2bf(float f) {           // RTNE float->bf16
    u32 u = __builtin_bit_cast(u32, f);
    u += 0x7fffu + ((u >> 16) & 1u);
    return (u16)(u >> 16);
}
__device__ __forceinline__ float bf2f(u16 b) {
    return __builtin_bit_cast(float, (u32)b << 16);
}
// pack two floats' top halves (truncating bf16) into one u32: low16=lo, high16=hi
__device__ __forceinline__ u32 pack2bf(float lo, float hi) {
    return __builtin_amdgcn_perm(__builtin_bit_cast(u32, hi),
                                 __builtin_bit_cast(u32, lo), 0x07060302u);
}

// async global->LDS, 16 B per lane; LDS dest = wave-uniform base + lane*16.
__device__ __forceinline__ void glds16(const u16* g, const u16* l) {
    __builtin_amdgcn_global_load_lds(
        (const __attribute__((address_space(1))) void*)(u64)g,
        (__attribute__((address_space(3))) void*)(u32)(u64)l, 16, 0, 0);
}

// ---------------------------------------------------------------------------
// Prepass A: bias[b,q,k] = adj ? rel_table[relpos] : -1e9   (bf16)
// ---------------------------------------------------------------------------
__global__ __launch_bounds__(256) void bias_prep(
    const int* __restrict__ adj, const int* __restrict__ relpos,
    const float* __restrict__ rel_table, u16* __restrict__ bias)
{
    __shared__ float tbl[8];
    int t = threadIdx.x;
    if (t < 6) tbl[t] = rel_table[t];
    __syncthreads();
    int idx = blockIdx.x * 256 + t;            // per 4 elements
    int4 a  = ((const int4*)adj)[idx];
    int4 rp = ((const int4*)relpos)[idx];
    u16x4 o;
    o.x = a.x ? f2bf(tbl[rp.x]) : f2bf(NEGINF);
    o.y = a.y ? f2bf(tbl[rp.y]) : f2bf(NEGINF);
    o.z = a.z ? f2bf(tbl[rp.z]) : f2bf(NEGINF);
    o.w = a.w ? f2bf(tbl[rp.w]) : f2bf(NEGINF);
    ((u16x4*)bias)[idx] = o;
}

// ---------------------------------------------------------------------------
// Prepass B: hid fp32 -> bf16
// ---------------------------------------------------------------------------
__global__ __launch_bounds__(256) void hid2bf(const float* __restrict__ in,
                                              u16* __restrict__ out)
{
    int idx = blockIdx.x * 256 + threadIdx.x;  // per 8 elements
    float4 a = ((const float4*)in)[2 * idx];
    float4 b = ((const float4*)in)[2 * idx + 1];
    u16x8 o;
    o[0] = f2bf(a.x); o[1] = f2bf(a.y); o[2] = f2bf(a.z); o[3] = f2bf(a.w);
    o[4] = f2bf(b.x); o[5] = f2bf(b.y); o[6] = f2bf(b.z); o[7] = f2bf(b.w);
    ((u16x8*)out)[idx] = o;
}

// ---------------------------------------------------------------------------
// Prepass C: W [K,N] fp32 -> W^T [N,K] bf16   (z selects q/k/v)
// ---------------------------------------------------------------------------
__global__ __launch_bounds__(256) void wtrans(
    const float* __restrict__ Wq, const float* __restrict__ Wk,
    const float* __restrict__ Wv, u16* __restrict__ WqT,
    u16* __restrict__ WkT, u16* __restrict__ WvT)
{
    const float* W; u16* WT;
    if (blockIdx.z == 0)      { W = Wq; WT = WqT; }
    else if (blockIdx.z == 1) { W = Wk; WT = WkT; }
    else                      { W = Wv; WT = WvT; }
    __shared__ float tile[32][33];
    int tx = threadIdx.x, ty = threadIdx.y;    // (32, 8)
    int n0 = blockIdx.x * 32, k0 = blockIdx.y * 32;
#pragma unroll
    for (int i = 0; i < 4; ++i) {
        int r = ty + i * 8;
        tile[r][tx] = W[(size_t)(k0 + r) * Dc + n0 + tx];
    }
    __syncthreads();
#pragma unroll
    for (int i = 0; i < 4; ++i) {
        int n = ty + i * 8;
        WT[(size_t)(n0 + n) * Dc + k0 + tx] = f2bf(tile[tx][n]);
    }
}

// ---------------------------------------------------------------------------
// Kernel 1: fused QKV projection (m97-structure), C = hid @ [Wq|Wk|Wv].
// v out: bf16 [B,H,DH,N] with each 64-aligned N-block internally permuted by
// sigma(r) = (r%16)*4 + r/16 so attention's P-store vectorization works.
// ---------------------------------------------------------------------------
__global__ __launch_bounds__(256) void qkv_mfma(
    const u16* __restrict__ hidb, const u16* __restrict__ WqT,
    const u16* __restrict__ WkT, const u16* __restrict__ WvT,
    u16* __restrict__ qo, u16* __restrict__ ko, u16* __restrict__ vo)
{
    __shared__ u16 As[128 * 64];
    __shared__ u16 Bs[128 * 64];

    const int bx = blockIdx.x, by = blockIdx.y;
    const int z = bx >> 3;
    const int c0 = (bx << 7) & 1023;          // within-z col base
    const int row0 = by << 7;                 // global row base (b*N + n)
    const u16* WT; u16* out;
    if (z == 0)      { WT = WqT; out = qo; }
    else if (z == 1) { WT = WkT; out = ko; }
    else             { WT = WvT; out = vo; }

    const int tid = threadIdx.x;
    const int wave = tid >> 6, lane = tid & 63;
    const int g = lane >> 4, li = lane & 15;
    const int wr = wave >> 1, wc = wave & 1;
    const int lr = lane >> 3, ls = lane & 7;  // staging: row-in-group, seg
    const int sseg = ls ^ lr;                 // swizzled k-segment to fetch

    const u16* pa = hidb + (size_t)(row0 + wave * 32 + lr) * Dc + sseg * 8;
    const u16* pb = WT   + (size_t)(c0   + wave * 32 + lr) * Dc + sseg * 8;
    u16* la = &As[(wave * 32) * 64];
    u16* lb = &Bs[(wave * 32) * 64];

    f32x4 acc[4][4] = {};

    const int swz = (li & 7);                 // fragment-read swizzle key

    for (int kt = 0; kt < Dc; kt += 64) {
        __syncthreads();
#pragma unroll
        for (int i = 0; i < 4; ++i) {
            glds16(pa + kt + i * 8 * Dc, la + i * 8 * 64);
            glds16(pb + kt + i * 8 * Dc, lb + i * 8 * 64);
        }
        __syncthreads();
#pragma unroll
        for (int ks = 0; ks < 2; ++ks) {
            const int soff = ((ks * 4 + g) ^ swz) * 8;
            bf16x8 af[4], bf[4];
#pragma unroll
            for (int mi = 0; mi < 4; ++mi)
                af[mi] = *(const bf16x8*)&As[(wr * 64 + mi * 16 + li) * 64 + soff];
#pragma unroll
            for (int nj = 0; nj < 4; ++nj)
                bf[nj] = *(const bf16x8*)&Bs[(wc * 64 + nj * 16 + li) * 64 + soff];
#pragma unroll
            for (int mi = 0; mi < 4; ++mi)
#pragma unroll
                for (int nj = 0; nj < 4; ++nj)
                    acc[mi][nj] = __builtin_amdgcn_mfma_f32_16x16x32_bf16(
                        af[mi], bf[nj], acc[mi][nj], 0, 0, 0);
        }
    }

    const int b = row0 >> 10;

    if (z != 2) {
        const int nbase = (row0 & 1023) + wr * 64 + g * 4;
#pragma unroll
        for (int mi = 0; mi < 4; ++mi)
#pragma unroll
            for (int rr = 0; rr < 4; ++rr) {
                int n = nbase + mi * 16 + rr;
#pragma unroll
                for (int nj = 0; nj < 4; ++nj) {
                    int cz = c0 + wc * 64 + nj * 16 + li;
                    out[(((size_t)(b * Hc + (cz >> 6)) * Nc + n) * DHc) + (cz & 63)]
                        = f2bf(acc[mi][nj][rr]);
                }
            }
    } else {
        // per-wave 64x64 transpose in LDS scratch; key dim stored in
        // sigma-permuted order: value at local key r lands at position
        // sigma(r) = (r&15)*4 + (r>>4), with the usual XOR seg swizzle.
        __syncthreads();
        u16* T = ((wave & 2) ? Bs : As) + (wave & 1) * 4096;
#pragma unroll
        for (int mi = 0; mi < 4; ++mi)
#pragma unroll
            for (int rr = 0; rr < 4; ++rr) {
                int r = mi * 16 + g * 4 + rr;
                int pp = ((r & 15) << 2) | (r >> 4);     // sigma(r)
#pragma unroll
                for (int nj = 0; nj < 4; ++nj) {
                    int c = nj * 16 + li;
                    T[c * 64 + ((((pp >> 3) ^ (c & 7)) << 3) | (pp & 7))]
                        = f2bf(acc[mi][nj][rr]);
                }
            }
        const int nseg = ls ^ lr;
#pragma unroll
        for (int i = 0; i < 8; ++i) {
            int cl = i * 8 + lr;              // local col (d)
            u16x8 val = *(const u16x8*)&T[cl * 64 + ls * 8];
            int cz = c0 + wc * 64 + cl;
            int n = (row0 & 1023) + wr * 64 + nseg * 8;
            *(u16x8*)&out[(((size_t)(b * Hc + (cz >> 6)) * DHc + (cz & 63)) * Nc) + n] = val;
        }
    }
}

// ---------------------------------------------------------------------------
// Kernel 2: flash attention v2. 128-q tile, 4 waves (wave owns 32 q-rows).
// Fixed-max softmax (max==0 safe; masked -> exp underflow to 0).
// K/V^T staged via global_load_lds with XOR swizzle; bias read per-element
// from global (VMEM, not LDS); P stored vectorized (b64) in sigma key-space,
// V arrives pre-permuted from qkv. P-tile LDS overlays the Q staging area.
// Grid 1024 (1D), remapped so the 8 q-tiles of each (b,h) share an XCD.
// ---------------------------------------------------------------------------
__global__ __launch_bounds__(256, 4) void attn_mfma(
    const u16* __restrict__ q, const u16* __restrict__ k,
    const u16* __restrict__ v, const u16* __restrict__ bias,
    float* __restrict__ attn_out)
{
    __shared__ u16 Ks[64 * 64];    // [key][kseg^(key&7)]
    __shared__ u16 VTs[64 * 64];   // [d][pkseg^(d&7)]  (sigma key-space)
    __shared__ u16 PQ[128 * 72];   // Q staging, then P tile [qrow][pkey]

    const int tid = threadIdx.x;
    const int w = tid >> 6, lane = tid & 63;
    const int g = lane >> 4, li = lane & 15;
    const int lr8 = lane >> 3, ls8 = lane & 7;
    const int lseg = ls8 ^ lr8;               // swizzled staging k-seg

    // XCD-locality remap: all 8 q-tiles of pair (b,h) share id%8
    const int id = blockIdx.x;
    const int p  = (id & 7) | ((id >> 6) << 3);   // 0..127 = b*16+h
    const int qt = (id >> 3) & 7;
    const int b = p >> 4, h = p & 15;
    const int q0 = qt << 7;

    // ---- stage Q [128][64] into PQ (stride 72) ----
    {
        const int sr = tid >> 1;
        const int sh = (tid & 1) * 32;
        const u16* qp = q + ((size_t)((b * Hc + h) * Nc) + q0 + sr) * DHc + sh;
        u16x8 a0 = *(const u16x8*)qp;
        u16x8 a1 = *(const u16x8*)(qp + 8);
        u16x8 a2 = *(const u16x8*)(qp + 16);
        u16x8 a3 = *(const u16x8*)(qp + 24);
        u16* dst = &PQ[sr * 72 + sh];
        *(u16x8*)(dst)      = a0; *(u16x8*)(dst + 8)  = a1;
        *(u16x8*)(dst + 16) = a2; *(u16x8*)(dst + 24) = a3;
    }
    __syncthreads();

    bf16x8 qf[2][2];
#pragma unroll
    for (int mt = 0; mt < 2; ++mt)
#pragma unroll
        for (int ks = 0; ks < 2; ++ks)
            qf[mt][ks] = *(const bf16x8*)&PQ[(w * 32 + mt * 16 + li) * 72 + ks * 32 + g * 8];
    // loop-top barrier covers PQ reuse (P writes happen after it)

    f32x4 o_[2][4] = {};
    float lsum[2][4] = {};

    const float scale = 0.03125f;  // 1/sqrt(1024)
    const u16* kbase = k + (size_t)(b * Hc + h) * Nc * DHc;
    const u16* vbase = v + (size_t)(b * Hc + h) * DHc * Nc;
    const u16* brow  = bias + ((size_t)(b * Nc) + q0 + w * 32) * Nc + li;

    for (int k0 = 0; k0 < Nc; k0 += 64) {
        __syncthreads();   // prev frag reads (and Q-frag reads) complete
        {
            const u16* kp = kbase + (size_t)(k0 + w * 16 + lr8) * DHc + lseg * 8;
            const u16* vp = vbase + (size_t)(w * 16 + lr8) * Nc + k0 + lseg * 8;
            u16* kl = &Ks[(w * 16) * 64];
            u16* vl = &VTs[(w * 16) * 64];
            glds16(kp,           kl);
            glds16(kp + 8 * DHc, kl + 8 * 64);
            glds16(vp,           vl);
            glds16(vp + 8 * Nc,  vl + 8 * 64);
        }
        __syncthreads();

        // --- S = Q.K^T : 16 MFMA, 8 K-frag b128 reads ---
        f32x4 sacc[2][4] = {};
#pragma unroll
        for (int ks = 0; ks < 2; ++ks) {
            const int so = (((ks << 2) | g) ^ (li & 7)) << 3;
#pragma unroll
            for (int nt = 0; nt < 4; ++nt) {
                bf16x8 kf = *(const bf16x8*)&Ks[(nt * 16 + li) * 64 + so];
                sacc[0][nt] = __builtin_amdgcn_mfma_f32_16x16x32_bf16(qf[0][ks], kf, sacc[0][nt], 0, 0, 0);
                sacc[1][nt] = __builtin_amdgcn_mfma_f32_16x16x32_bf16(qf[1][ks], kf, sacc[1][nt], 0, 0, 0);
            }
        }

        // --- softmax: bias from global (VMEM), P packed to b64 in sigma-space ---
#pragma unroll
        for (int mt = 0; mt < 2; ++mt)
#pragma unroll
            for (int r = 0; r < 4; ++r) {
                const int qrl = mt * 16 + g * 4 + r;
                const u16* bp = brow + (size_t)qrl * Nc + k0;
                float pv[4];
#pragma unroll
                for (int nt = 0; nt < 4; ++nt) {
                    float sv = sacc[mt][nt][r] * scale + bf2f(bp[nt * 16]);
                    pv[nt] = __expf(sv);
                    lsum[mt][r] += pv[nt];
                }
                u32* dst = (u32*)&PQ[(w * 32 + qrl) * 72 + li * 4];
                dst[0] = pack2bf(pv[0], pv[1]);
                dst[1] = pack2bf(pv[2], pv[3]);
            }

        // --- O += P.V : 16 MFMA, 4 P-frag + 8 VT-frag b128 reads ---
#pragma unroll
        for (int ks = 0; ks < 2; ++ks) {
            const int so = (((ks << 2) | g) ^ (li & 7)) << 3;
            bf16x8 pa0 = *(const bf16x8*)&PQ[(w * 32 + li) * 72 + ks * 32 + g * 8];
            bf16x8 pa1 = *(const bf16x8*)&PQ[(w * 32 + 16 + li) * 72 + ks * 32 + g * 8];
#pragma unroll
            for (int j = 0; j < 4; ++j) {
                bf16x8 vf = *(const bf16x8*)&VTs[(j * 16 + li) * 64 + so];
                o_[0][j] = __builtin_amdgcn_mfma_f32_16x16x32_bf16(pa0, vf, o_[0][j], 0, 0, 0);
                o_[1][j] = __builtin_amdgcn_mfma_f32_16x16x32_bf16(pa1, vf, o_[1][j], 0, 0, 0);
            }
        }
    }

    // --- epilogue: reduce row sums across 16 li lanes, normalize, write ---
#pragma unroll
    for (int mt = 0; mt < 2; ++mt)
#pragma unroll
        for (int r = 0; r < 4; ++r) {
            float l = lsum[mt][r];
            l += __shfl_xor(l, 1);
            l += __shfl_xor(l, 2);
            l += __shfl_xor(l, 4);
            l += __shfl_xor(l, 8);
            float inv = 1.f / l;
            int qrow = q0 + w * 32 + mt * 16 + g * 4 + r;
            float* op = attn_out + ((size_t)b * Nc + qrow) * Dc + h * DHc;
#pragma unroll
            for (int j = 0; j < 4; ++j)
                op[j * 16 + li] = o_[mt][j][r] * inv;
        }
}

// ---------------------------------------------------------------------------
// Kernel 3: out = LayerNorm(relu(attn_out) + hid), in-place safe.
// ---------------------------------------------------------------------------
__global__ __launch_bounds__(256) void ln_kernel(
    const float* attn_out, const float* __restrict__ hid,
    const float* __restrict__ gamma, const float* __restrict__ beta,
    float* out)
{
    const int row = blockIdx.x;
    const int t = threadIdx.x;

    float4 av = *(const float4*)&attn_out[(size_t)row * Dc + t * 4];
    float4 hv = *(const float4*)&hid[(size_t)row * Dc + t * 4];
    float x0 = fmaxf(av.x, 0.f) + hv.x;
    float x1 = fmaxf(av.y, 0.f) + hv.y;
    float x2 = fmaxf(av.z, 0.f) + hv.z;
    float x3 = fmaxf(av.w, 0.f) + hv.w;

    float s1 = x0 + x1 + x2 + x3;
    float s2 = x0 * x0 + x1 * x1 + x2 * x2 + x3 * x3;
#pragma unroll
    for (int off = 1; off < 64; off <<= 1) {
        s1 += __shfl_xor(s1, off);
        s2 += __shfl_xor(s2, off);
    }
    __shared__ float w1[4], w2[4];
    int lane = t & 63, wid = t >> 6;
    if (lane == 0) { w1[wid] = s1; w2[wid] = s2; }
    __syncthreads();
    s1 = w1[0] + w1[1] + w1[2] + w1[3];
    s2 = w2[0] + w2[1] + w2[2] + w2[3];

    float mu  = s1 * (1.f / 1024.f);
    float var = s2 * (1.f / 1024.f) - mu * mu;
    float rstd = rsqrtf(var + 1e-5f);

    float4 g  = *(const float4*)&gamma[t * 4];
    float4 be = *(const float4*)&beta[t * 4];
    float4 r4;
    r4.x = (x0 - mu) * rstd * g.x + be.x;
    r4.y = (x1 - mu) * rstd * g.y + be.y;
    r4.z = (x2 - mu) * rstd * g.z + be.z;
    r4.w = (x3 - mu) * rstd * g.w + be.w;
    *(float4*)&out[(size_t)row * Dc + t * 4] = r4;
}

extern "C" void kernel_launch(void* const* d_in, const int* in_sizes, int n_in,
                              void* d_out, int out_size, void* d_ws, size_t ws_size,
                              hipStream_t stream) {
    const float* hid       = (const float*)d_in[0];
    const int*   adj       = (const int*)d_in[1];
    const int*   relpos    = (const int*)d_in[2];
    const float* Wq        = (const float*)d_in[3];
    const float* Wk        = (const float*)d_in[4];
    const float* Wv        = (const float*)d_in[5];
    const float* rel_table = (const float*)d_in[6];
    const float* gamma     = (const float*)d_in[7];
    const float* beta      = (const float*)d_in[8];
    float* out = (float*)d_out;

    const size_t per  = (size_t)Bc * Hc * Nc * DHc;  // 8,388,608
    const size_t wsz  = (size_t)Dc * Dc;             // 1,048,576
    u16* qb   = (u16*)d_ws;
    u16* kb   = qb + per;
    u16* vb   = kb + per;                 // [B,H,DH,N] transposed+sigma-permuted
    u16* bias = vb + per;                 // B*N*N
    u16* hidb = bias + (size_t)Bc * Nc * Nc;
    u16* wqT  = hidb + (size_t)Bc * Nc * Dc;
    u16* wkT  = wqT + wsz;
    u16* wvT  = wkT + wsz;
    // total ws: ~90.2 MB

    bias_prep<<<(Bc * Nc * Nc) / (4 * 256), 256, 0, stream>>>(adj, relpos, rel_table, bias);
    hid2bf<<<(Bc * Nc * Dc) / (8 * 256), 256, 0, stream>>>(hid, hidb);
    wtrans<<<dim3(32, 32, 3), dim3(32, 8), 0, stream>>>(Wq, Wk, Wv, wqT, wkT, wvT);
    qkv_mfma<<<dim3(24, 64), 256, 0, stream>>>(hidb, wqT, wkT, wvT, qb, kb, vb);
    attn_mfma<<<1024, 256, 0, stream>>>(qb, kb, vb, bias, out);
    ln_kernel<<<Bc * Nc, 256, 0, stream>>>(out, hid, gamma, beta, out);
}

// Round 6
// 298.274 us; speedup vs baseline: 1.1339x; 1.1339x over previous
//
#include <hip/hip_runtime.h>
#include <math.h>

#define Bc 8
#define Nc 1024
#define Dc 1024
#define Hc 16
#define DHc 64
#define NEGINF -1e9f

typedef unsigned int  u32;
typedef unsigned short u16;
typedef unsigned long long u64;
typedef u16  u16x8 __attribute__((ext_vector_type(8)));
typedef u16  u16x4 __attribute__((ext_vector_type(4)));
typedef __bf16 bf16x8 __attribute__((ext_vector_type(8)));
typedef float f32x4 __attribute__((ext_vector_type(4)));

__device__ __forceinline__ u16 f2bf(float f) {           // RTNE float->bf16
    u32 u = __builtin_bit_cast(u32, f);
    u += 0x7fffu + ((u >> 16) & 1u);
    return (u16)(u >> 16);
}
__device__ __forceinline__ float bf2f(u16 b) {
    return __builtin_bit_cast(float, (u32)b << 16);
}
// pack two floats' top halves (truncating bf16) into one u32: low16=lo, high16=hi
__device__ __forceinline__ u32 pack2bf(float lo, float hi) {
    return __builtin_amdgcn_perm(__builtin_bit_cast(u32, hi),
                                 __builtin_bit_cast(u32, lo), 0x07060302u);
}

// async global->LDS, 16 B per lane; LDS dest = wave-uniform base + lane*16.
__device__ __forceinline__ void glds16(const u16* g, const u16* l) {
    __builtin_amdgcn_global_load_lds(
        (const __attribute__((address_space(1))) void*)(u64)g,
        (__attribute__((address_space(3))) void*)(u32)(u64)l, 16, 0, 0);
}

// ---------------------------------------------------------------------------
// Prepass A: sigma-permuted bias.  Within each 64-aligned key block, plain
// key k lands at position 4*(k&15) + (k>>4)  (same sigma as V / P tiles), so
// attention reads its 4 per-row bias values as ONE contiguous u16x4.
// Each thread gathers 4 inputs (keys m, m+16, m+32, m+48) -> one u16x4 out.
// ---------------------------------------------------------------------------
__global__ __launch_bounds__(256) void bias_prep(
    const int* __restrict__ adj, const int* __restrict__ relpos,
    const float* __restrict__ rel_table, u16* __restrict__ bias)
{
    __shared__ float tbl[8];
    int t = threadIdx.x;
    if (t < 6) tbl[t] = rel_table[t];
    __syncthreads();
    int i = blockIdx.x * 256 + t;              // one u16x4 output
    int pos4 = i << 2;
    int row  = pos4 >> 10;                     // b*N + q
    int p    = pos4 & 1023;
    int blk  = p & ~63;                        // 64-block base
    int m    = (p & 63) >> 2;                  // 0..15
    size_t base = ((size_t)row << 10) + blk + m;
    u16x4 o;
#pragma unroll
    for (int j = 0; j < 4; ++j) {              // element j <- plain key 16j+m
        int a  = adj[base + 16 * j];
        int rp = relpos[base + 16 * j];
        o[j] = a ? f2bf(tbl[rp]) : f2bf(NEGINF);
    }
    ((u16x4*)bias)[i] = o;
}

// ---------------------------------------------------------------------------
// Prepass B: hid fp32 -> bf16
// ---------------------------------------------------------------------------
__global__ __launch_bounds__(256) void hid2bf(const float* __restrict__ in,
                                              u16* __restrict__ out)
{
    int idx = blockIdx.x * 256 + threadIdx.x;  // per 8 elements
    float4 a = ((const float4*)in)[2 * idx];
    float4 b = ((const float4*)in)[2 * idx + 1];
    u16x8 o;
    o[0] = f2bf(a.x); o[1] = f2bf(a.y); o[2] = f2bf(a.z); o[3] = f2bf(a.w);
    o[4] = f2bf(b.x); o[5] = f2bf(b.y); o[6] = f2bf(b.z); o[7] = f2bf(b.w);
    ((u16x8*)out)[idx] = o;
}

// ---------------------------------------------------------------------------
// Prepass C: W [K,N] fp32 -> W^T [N,K] bf16   (z selects q/k/v)
// ---------------------------------------------------------------------------
__global__ __launch_bounds__(256) void wtrans(
    const float* __restrict__ Wq, const float* __restrict__ Wk,
    const float* __restrict__ Wv, u16* __restrict__ WqT,
    u16* __restrict__ WkT, u16* __restrict__ WvT)
{
    const float* W; u16* WT;
    if (blockIdx.z == 0)      { W = Wq; WT = WqT; }
    else if (blockIdx.z == 1) { W = Wk; WT = WkT; }
    else                      { W = Wv; WT = WvT; }
    __shared__ float tile[32][33];
    int tx = threadIdx.x, ty = threadIdx.y;    // (32, 8)
    int n0 = blockIdx.x * 32, k0 = blockIdx.y * 32;
#pragma unroll
    for (int i = 0; i < 4; ++i) {
        int r = ty + i * 8;
        tile[r][tx] = W[(size_t)(k0 + r) * Dc + n0 + tx];
    }
    __syncthreads();
#pragma unroll
    for (int i = 0; i < 4; ++i) {
        int n = ty + i * 8;
        WT[(size_t)(n0 + n) * Dc + k0 + tx] = f2bf(tile[tx][n]);
    }
}

// ---------------------------------------------------------------------------
// Kernel 1: fused QKV projection (m97-structure), C = hid @ [Wq|Wk|Wv].
// v out: bf16 [B,H,DH,N] with each 64-aligned N-block internally permuted by
// sigma(r) = (r%16)*4 + r/16 so attention's P-store vectorization works.
// ---------------------------------------------------------------------------
__global__ __launch_bounds__(256) void qkv_mfma(
    const u16* __restrict__ hidb, const u16* __restrict__ WqT,
    const u16* __restrict__ WkT, const u16* __restrict__ WvT,
    u16* __restrict__ qo, u16* __restrict__ ko, u16* __restrict__ vo)
{
    __shared__ u16 As[128 * 64];
    __shared__ u16 Bs[128 * 64];

    const int bx = blockIdx.x, by = blockIdx.y;
    const int z = bx >> 3;
    const int c0 = (bx << 7) & 1023;          // within-z col base
    const int row0 = by << 7;                 // global row base (b*N + n)
    const u16* WT; u16* out;
    if (z == 0)      { WT = WqT; out = qo; }
    else if (z == 1) { WT = WkT; out = ko; }
    else             { WT = WvT; out = vo; }

    const int tid = threadIdx.x;
    const int wave = tid >> 6, lane = tid & 63;
    const int g = lane >> 4, li = lane & 15;
    const int wr = wave >> 1, wc = wave & 1;
    const int lr = lane >> 3, ls = lane & 7;  // staging: row-in-group, seg
    const int sseg = ls ^ lr;                 // swizzled k-segment to fetch

    const u16* pa = hidb + (size_t)(row0 + wave * 32 + lr) * Dc + sseg * 8;
    const u16* pb = WT   + (size_t)(c0   + wave * 32 + lr) * Dc + sseg * 8;
    u16* la = &As[(wave * 32) * 64];
    u16* lb = &Bs[(wave * 32) * 64];

    f32x4 acc[4][4] = {};

    const int swz = (li & 7);                 // fragment-read swizzle key

    for (int kt = 0; kt < Dc; kt += 64) {
        __syncthreads();
#pragma unroll
        for (int i = 0; i < 4; ++i) {
            glds16(pa + kt + i * 8 * Dc, la + i * 8 * 64);
            glds16(pb + kt + i * 8 * Dc, lb + i * 8 * 64);
        }
        __syncthreads();
#pragma unroll
        for (int ks = 0; ks < 2; ++ks) {
            const int soff = ((ks * 4 + g) ^ swz) * 8;
            bf16x8 af[4], bf[4];
#pragma unroll
            for (int mi = 0; mi < 4; ++mi)
                af[mi] = *(const bf16x8*)&As[(wr * 64 + mi * 16 + li) * 64 + soff];
#pragma unroll
            for (int nj = 0; nj < 4; ++nj)
                bf[nj] = *(const bf16x8*)&Bs[(wc * 64 + nj * 16 + li) * 64 + soff];
#pragma unroll
            for (int mi = 0; mi < 4; ++mi)
#pragma unroll
                for (int nj = 0; nj < 4; ++nj)
                    acc[mi][nj] = __builtin_amdgcn_mfma_f32_16x16x32_bf16(
                        af[mi], bf[nj], acc[mi][nj], 0, 0, 0);
        }
    }

    const int b = row0 >> 10;

    if (z != 2) {
        const int nbase = (row0 & 1023) + wr * 64 + g * 4;
#pragma unroll
        for (int mi = 0; mi < 4; ++mi)
#pragma unroll
            for (int rr = 0; rr < 4; ++rr) {
                int n = nbase + mi * 16 + rr;
#pragma unroll
                for (int nj = 0; nj < 4; ++nj) {
                    int cz = c0 + wc * 64 + nj * 16 + li;
                    out[(((size_t)(b * Hc + (cz >> 6)) * Nc + n) * DHc) + (cz & 63)]
                        = f2bf(acc[mi][nj][rr]);
                }
            }
    } else {
        // per-wave 64x64 transpose in LDS scratch; key dim stored in
        // sigma-permuted order with the usual XOR seg swizzle.
        __syncthreads();
        u16* T = ((wave & 2) ? Bs : As) + (wave & 1) * 4096;
#pragma unroll
        for (int mi = 0; mi < 4; ++mi)
#pragma unroll
            for (int rr = 0; rr < 4; ++rr) {
                int r = mi * 16 + g * 4 + rr;
                int pp = ((r & 15) << 2) | (r >> 4);     // sigma(r)
#pragma unroll
                for (int nj = 0; nj < 4; ++nj) {
                    int c = nj * 16 + li;
                    T[c * 64 + ((((pp >> 3) ^ (c & 7)) << 3) | (pp & 7))]
                        = f2bf(acc[mi][nj][rr]);
                }
            }
        const int nseg = ls ^ lr;
#pragma unroll
        for (int i = 0; i < 8; ++i) {
            int cl = i * 8 + lr;              // local col (d)
            u16x8 val = *(const u16x8*)&T[cl * 64 + ls * 8];
            int cz = c0 + wc * 64 + cl;
            int n = (row0 & 1023) + wr * 64 + nseg * 8;
            *(u16x8*)&out[(((size_t)(b * Hc + (cz >> 6)) * DHc + (cz & 63)) * Nc) + n] = val;
        }
    }
}

// ---------------------------------------------------------------------------
// Kernel 2: flash attention v2.1. 128-q tile, 4 waves (wave owns 32 q-rows).
// Fixed-max softmax (max==0 safe; masked -> exp underflow to 0).
// K/V^T staged via global_load_lds with XOR swizzle. Bias is sigma-permuted
// in global: ONE u16x4 load per row per tile, issued right after the glds so
// its latency drains with the staging barrier (registers by softmax time).
// P stored vectorized (b64) in sigma key-space; V arrives pre-permuted.
// Grid 1024 (1D), remapped so the 8 q-tiles of each (b,h) share an XCD.
// ---------------------------------------------------------------------------
__global__ __launch_bounds__(256, 4) void attn_mfma(
    const u16* __restrict__ q, const u16* __restrict__ k,
    const u16* __restrict__ v, const u16* __restrict__ bias,
    float* __restrict__ attn_out)
{
    __shared__ u16 Ks[64 * 64];    // [key][kseg^(key&7)]
    __shared__ u16 VTs[64 * 64];   // [d][pkseg^(d&7)]  (sigma key-space)
    __shared__ u16 PQ[128 * 72];   // Q staging, then P tile [qrow][pkey]

    const int tid = threadIdx.x;
    const int w = tid >> 6, lane = tid & 63;
    const int g = lane >> 4, li = lane & 15;
    const int lr8 = lane >> 3, ls8 = lane & 7;
    const int lseg = ls8 ^ lr8;               // swizzled staging k-seg

    // XCD-locality remap: all 8 q-tiles of pair (b,h) share id%8
    const int id = blockIdx.x;
    const int p  = (id & 7) | ((id >> 6) << 3);   // 0..127 = b*16+h
    const int qt = (id >> 3) & 7;
    const int b = p >> 4, h = p & 15;
    const int q0 = qt << 7;

    // ---- stage Q [128][64] into PQ (stride 72) ----
    {
        const int sr = tid >> 1;
        const int sh = (tid & 1) * 32;
        const u16* qp = q + ((size_t)((b * Hc + h) * Nc) + q0 + sr) * DHc + sh;
        u16x8 a0 = *(const u16x8*)qp;
        u16x8 a1 = *(const u16x8*)(qp + 8);
        u16x8 a2 = *(const u16x8*)(qp + 16);
        u16x8 a3 = *(const u16x8*)(qp + 24);
        u16* dst = &PQ[sr * 72 + sh];
        *(u16x8*)(dst)      = a0; *(u16x8*)(dst + 8)  = a1;
        *(u16x8*)(dst + 16) = a2; *(u16x8*)(dst + 24) = a3;
    }
    __syncthreads();

    bf16x8 qf[2][2];
#pragma unroll
    for (int mt = 0; mt < 2; ++mt)
#pragma unroll
        for (int ks = 0; ks < 2; ++ks)
            qf[mt][ks] = *(const bf16x8*)&PQ[(w * 32 + mt * 16 + li) * 72 + ks * 32 + g * 8];

    f32x4 o_[2][4] = {};
    float lsum[2][4] = {};

    const float scale = 0.03125f;  // 1/sqrt(1024)
    const u16* kbase = k + (size_t)(b * Hc + h) * Nc * DHc;
    const u16* vbase = v + (size_t)(b * Hc + h) * DHc * Nc;
    const u16* brow  = bias + ((size_t)(b * Nc) + q0 + w * 32) * Nc + 4 * li;

    for (int k0 = 0; k0 < Nc; k0 += 64) {
        __syncthreads();   // prev frag reads complete
        {
            const u16* kp = kbase + (size_t)(k0 + w * 16 + lr8) * DHc + lseg * 8;
            const u16* vp = vbase + (size_t)(w * 16 + lr8) * Nc + k0 + lseg * 8;
            u16* kl = &Ks[(w * 16) * 64];
            u16* vl = &VTs[(w * 16) * 64];
            glds16(kp,           kl);
            glds16(kp + 8 * DHc, kl + 8 * 64);
            glds16(vp,           vl);
            glds16(vp + 8 * Nc,  vl + 8 * 64);
        }
        // bias prefetch into registers — drains with the same barrier below
        u16x4 brv[2][4];
#pragma unroll
        for (int mt = 0; mt < 2; ++mt)
#pragma unroll
            for (int r = 0; r < 4; ++r)
                brv[mt][r] = *(const u16x4*)&brow[(size_t)(mt * 16 + g * 4 + r) * Nc + k0];
        __syncthreads();

        // --- S = Q.K^T : 16 MFMA, 8 K-frag b128 reads ---
        f32x4 sacc[2][4] = {};
#pragma unroll
        for (int ks = 0; ks < 2; ++ks) {
            const int so = (((ks << 2) | g) ^ (li & 7)) << 3;
#pragma unroll
            for (int nt = 0; nt < 4; ++nt) {
                bf16x8 kf = *(const bf16x8*)&Ks[(nt * 16 + li) * 64 + so];
                sacc[0][nt] = __builtin_amdgcn_mfma_f32_16x16x32_bf16(qf[0][ks], kf, sacc[0][nt], 0, 0, 0);
                sacc[1][nt] = __builtin_amdgcn_mfma_f32_16x16x32_bf16(qf[1][ks], kf, sacc[1][nt], 0, 0, 0);
            }
        }

        // --- softmax from registers; P packed to b64 in sigma-space ---
#pragma unroll
        for (int mt = 0; mt < 2; ++mt)
#pragma unroll
            for (int r = 0; r < 4; ++r) {
                const int qrl = mt * 16 + g * 4 + r;
                float pv[4];
#pragma unroll
                for (int nt = 0; nt < 4; ++nt) {
                    float sv = sacc[mt][nt][r] * scale + bf2f(brv[mt][r][nt]);
                    pv[nt] = __expf(sv);
                    lsum[mt][r] += pv[nt];
                }
                u32* dst = (u32*)&PQ[(w * 32 + qrl) * 72 + li * 4];
                dst[0] = pack2bf(pv[0], pv[1]);
                dst[1] = pack2bf(pv[2], pv[3]);
            }

        // --- O += P.V : 16 MFMA, 4 P-frag + 8 VT-frag b128 reads ---
#pragma unroll
        for (int ks = 0; ks < 2; ++ks) {
            const int so = (((ks << 2) | g) ^ (li & 7)) << 3;
            bf16x8 pa0 = *(const bf16x8*)&PQ[(w * 32 + li) * 72 + ks * 32 + g * 8];
            bf16x8 pa1 = *(const bf16x8*)&PQ[(w * 32 + 16 + li) * 72 + ks * 32 + g * 8];
#pragma unroll
            for (int j = 0; j < 4; ++j) {
                bf16x8 vf = *(const bf16x8*)&VTs[(j * 16 + li) * 64 + so];
                o_[0][j] = __builtin_amdgcn_mfma_f32_16x16x32_bf16(pa0, vf, o_[0][j], 0, 0, 0);
                o_[1][j] = __builtin_amdgcn_mfma_f32_16x16x32_bf16(pa1, vf, o_[1][j], 0, 0, 0);
            }
        }
    }

    // --- epilogue: reduce row sums across 16 li lanes, normalize, write ---
#pragma unroll
    for (int mt = 0; mt < 2; ++mt)
#pragma unroll
        for (int r = 0; r < 4; ++r) {
            float l = lsum[mt][r];
            l += __shfl_xor(l, 1);
            l += __shfl_xor(l, 2);
            l += __shfl_xor(l, 4);
            l += __shfl_xor(l, 8);
            float inv = 1.f / l;
            int qrow = q0 + w * 32 + mt * 16 + g * 4 + r;
            float* op = attn_out + ((size_t)b * Nc + qrow) * Dc + h * DHc;
#pragma unroll
            for (int j = 0; j < 4; ++j)
                op[j * 16 + li] = o_[mt][j][r] * inv;
        }
}

// ---------------------------------------------------------------------------
// Kernel 3: out = LayerNorm(relu(attn_out) + hid), in-place safe.
// ---------------------------------------------------------------------------
__global__ __launch_bounds__(256) void ln_kernel(
    const float* attn_out, const float* __restrict__ hid,
    const float* __restrict__ gamma, const float* __restrict__ beta,
    float* out)
{
    const int row = blockIdx.x;
    const int t = threadIdx.x;

    float4 av = *(const float4*)&attn_out[(size_t)row * Dc + t * 4];
    float4 hv = *(const float4*)&hid[(size_t)row * Dc + t * 4];
    float x0 = fmaxf(av.x, 0.f) + hv.x;
    float x1 = fmaxf(av.y, 0.f) + hv.y;
    float x2 = fmaxf(av.z, 0.f) + hv.z;
    float x3 = fmaxf(av.w, 0.f) + hv.w;

    float s1 = x0 + x1 + x2 + x3;
    float s2 = x0 * x0 + x1 * x1 + x2 * x2 + x3 * x3;
#pragma unroll
    for (int off = 1; off < 64; off <<= 1) {
        s1 += __shfl_xor(s1, off);
        s2 += __shfl_xor(s2, off);
    }
    __shared__ float w1[4], w2[4];
    int lane = t & 63, wid = t >> 6;
    if (lane == 0) { w1[wid] = s1; w2[wid] = s2; }
    __syncthreads();
    s1 = w1[0] + w1[1] + w1[2] + w1[3];
    s2 = w2[0] + w2[1] + w2[2] + w2[3];

    float mu  = s1 * (1.f / 1024.f);
    float var = s2 * (1.f / 1024.f) - mu * mu;
    float rstd = rsqrtf(var + 1e-5f);

    float4 g  = *(const float4*)&gamma[t * 4];
    float4 be = *(const float4*)&beta[t * 4];
    float4 r4;
    r4.x = (x0 - mu) * rstd * g.x + be.x;
    r4.y = (x1 - mu) * rstd * g.y + be.y;
    r4.z = (x2 - mu) * rstd * g.z + be.z;
    r4.w = (x3 - mu) * rstd * g.w + be.w;
    *(float4*)&out[(size_t)row * Dc + t * 4] = r4;
}

extern "C" void kernel_launch(void* const* d_in, const int* in_sizes, int n_in,
                              void* d_out, int out_size, void* d_ws, size_t ws_size,
                              hipStream_t stream) {
    const float* hid       = (const float*)d_in[0];
    const int*   adj       = (const int*)d_in[1];
    const int*   relpos    = (const int*)d_in[2];
    const float* Wq        = (const float*)d_in[3];
    const float* Wk        = (const float*)d_in[4];
    const float* Wv        = (const float*)d_in[5];
    const float* rel_table = (const float*)d_in[6];
    const float* gamma     = (const float*)d_in[7];
    const float* beta      = (const float*)d_in[8];
    float* out = (float*)d_out;

    const size_t per  = (size_t)Bc * Hc * Nc * DHc;  // 8,388,608
    const size_t wsz  = (size_t)Dc * Dc;             // 1,048,576
    u16* qb   = (u16*)d_ws;
    u16* kb   = qb + per;
    u16* vb   = kb + per;                 // [B,H,DH,N] transposed+sigma-permuted
    u16* bias = vb + per;                 // B*N*N sigma-permuted
    u16* hidb = bias + (size_t)Bc * Nc * Nc;
    u16* wqT  = hidb + (size_t)Bc * Nc * Dc;
    u16* wkT  = wqT + wsz;
    u16* wvT  = wkT + wsz;
    // total ws: ~90.2 MB

    bias_prep<<<(Bc * Nc * Nc) / (4 * 256), 256, 0, stream>>>(adj, relpos, rel_table, bias);
    hid2bf<<<(Bc * Nc * Dc) / (8 * 256), 256, 0, stream>>>(hid, hidb);
    wtrans<<<dim3(32, 32, 3), dim3(32, 8), 0, stream>>>(Wq, Wk, Wv, wqT, wkT, wvT);
    qkv_mfma<<<dim3(24, 64), 256, 0, stream>>>(hidb, wqT, wkT, wvT, qb, kb, vb);
    attn_mfma<<<1024, 256, 0, stream>>>(qb, kb, vb, bias, out);
    ln_kernel<<<Bc * Nc, 256, 0, stream>>>(out, hid, gamma, beta, out);
}

// Round 7
// 289.211 us; speedup vs baseline: 1.1694x; 1.0313x over previous
//
#include <hip/hip_runtime.h>
#include <math.h>

#define Bc 8
#define Nc 1024
#define Dc 1024
#define Hc 16
#define DHc 64
#define NEGINF -1e9f

typedef unsigned int  u32;
typedef unsigned short u16;
typedef unsigned long long u64;
typedef u16  u16x8 __attribute__((ext_vector_type(8)));
typedef u16  u16x4 __attribute__((ext_vector_type(4)));
typedef u32  u32x2 __attribute__((ext_vector_type(2)));
typedef __bf16 bf16x8 __attribute__((ext_vector_type(8)));
typedef float f32x4 __attribute__((ext_vector_type(4)));

__device__ __forceinline__ u16 f2bf(float f) {           // RTNE float->bf16
    u32 u = __builtin_bit_cast(u32, f);
    u += 0x7fffu + ((u >> 16) & 1u);
    return (u16)(u >> 16);
}
__device__ __forceinline__ float bf2f(u16 b) {
    return __builtin_bit_cast(float, (u32)b << 16);
}
// pack two floats' top halves (truncating bf16) into one u32: low16=lo, high16=hi
__device__ __forceinline__ u32 pack2bf(float lo, float hi) {
    return __builtin_amdgcn_perm(__builtin_bit_cast(u32, hi),
                                 __builtin_bit_cast(u32, lo), 0x07060302u);
}

// async global->LDS, 16 B per lane; LDS dest = wave-uniform base + lane*16.
__device__ __forceinline__ void glds16(const u16* g, const u16* l) {
    __builtin_amdgcn_global_load_lds(
        (const __attribute__((address_space(1))) void*)(u64)g,
        (__attribute__((address_space(3))) void*)(u32)(u64)l, 16, 0, 0);
}

// ---------------------------------------------------------------------------
// Fused prepasses (one kernel, branch on block range):
//  blocks [0, 8192):      sigma-permuted bias (key k -> 4*(k%16)+k/16 within
//                         each 64-block; one u16x4 out per thread)
//  blocks [8192, 12288):  hid fp32 -> bf16
//  blocks [12288, 15360): W -> W^T bf16 (z = q/k/v)
// ---------------------------------------------------------------------------
__global__ __launch_bounds__(256) void prep_fused(
    const int* __restrict__ adj, const int* __restrict__ relpos,
    const float* __restrict__ rel_table, u16* __restrict__ bias,
    const float* __restrict__ hid, u16* __restrict__ hidb,
    const float* __restrict__ Wq, const float* __restrict__ Wk,
    const float* __restrict__ Wv, u16* __restrict__ WqT,
    u16* __restrict__ WkT, u16* __restrict__ WvT)
{
    const int blk = blockIdx.x;
    const int t = threadIdx.x;

    if (blk < 8192) {
        __shared__ float tbl[8];
        if (t < 6) tbl[t] = rel_table[t];
        __syncthreads();
        int i = blk * 256 + t;                 // one u16x4 output
        int pos4 = i << 2;
        int row  = pos4 >> 10;                 // b*N + q
        int p    = pos4 & 1023;
        int blkb = p & ~63;
        int m    = (p & 63) >> 2;              // 0..15
        size_t base = ((size_t)row << 10) + blkb + m;
        u16x4 o;
#pragma unroll
        for (int j = 0; j < 4; ++j) {          // element j <- plain key 16j+m
            int a  = adj[base + 16 * j];
            int rp = relpos[base + 16 * j];
            o[j] = a ? f2bf(tbl[rp]) : f2bf(NEGINF);
        }
        ((u16x4*)bias)[i] = o;
    } else if (blk < 12288) {
        int idx = (blk - 8192) * 256 + t;      // per 8 elements
        float4 a = ((const float4*)hid)[2 * idx];
        float4 b = ((const float4*)hid)[2 * idx + 1];
        u16x8 o;
        o[0] = f2bf(a.x); o[1] = f2bf(a.y); o[2] = f2bf(a.z); o[3] = f2bf(a.w);
        o[4] = f2bf(b.x); o[5] = f2bf(b.y); o[6] = f2bf(b.z); o[7] = f2bf(b.w);
        ((u16x8*)hidb)[idx] = o;
    } else {
        __shared__ float tile[32][33];
        const int wb = blk - 12288;
        const int x = wb & 31, y = (wb >> 5) & 31, z = wb >> 10;
        const float* W; u16* WT;
        if (z == 0)      { W = Wq; WT = WqT; }
        else if (z == 1) { W = Wk; WT = WkT; }
        else             { W = Wv; WT = WvT; }
        const int tx = t & 31, ty = t >> 5;    // (32, 8)
        const int n0 = x * 32, k0 = y * 32;
#pragma unroll
        for (int i = 0; i < 4; ++i) {
            int r = ty + i * 8;
            tile[r][tx] = W[(size_t)(k0 + r) * Dc + n0 + tx];
        }
        __syncthreads();
#pragma unroll
        for (int i = 0; i < 4; ++i) {
            int n = ty + i * 8;
            WT[(size_t)(n0 + n) * Dc + k0 + tx] = f2bf(tile[tx][n]);
        }
    }
}

// ---------------------------------------------------------------------------
// Kernel 1: fused QKV projection (m97-structure), C = hid @ [Wq|Wk|Wv].
// q,k out: bf16 [B,H,N,DH] with d SIGMA-PERMUTED within each head's 64-block
// (d -> 4*(d%16)+d/16). Both operands of QK^T carry the same permutation so
// the attention dot product is unchanged; enables b64 packed epilogue stores.
// v out: bf16 [B,H,DH,N] with the key dim sigma-permuted per 64-block (for
// attention's vectorized P stores).
// ---------------------------------------------------------------------------
__global__ __launch_bounds__(256) void qkv_mfma(
    const u16* __restrict__ hidb, const u16* __restrict__ WqT,
    const u16* __restrict__ WkT, const u16* __restrict__ WvT,
    u16* __restrict__ qo, u16* __restrict__ ko, u16* __restrict__ vo)
{
    __shared__ u16 As[128 * 64];
    __shared__ u16 Bs[128 * 64];

    const int bx = blockIdx.x, by = blockIdx.y;
    const int z = bx >> 3;
    const int c0 = (bx << 7) & 1023;          // within-z col base
    const int row0 = by << 7;                 // global row base (b*N + n)
    const u16* WT; u16* out;
    if (z == 0)      { WT = WqT; out = qo; }
    else if (z == 1) { WT = WkT; out = ko; }
    else             { WT = WvT; out = vo; }

    const int tid = threadIdx.x;
    const int wave = tid >> 6, lane = tid & 63;
    const int g = lane >> 4, li = lane & 15;
    const int wr = wave >> 1, wc = wave & 1;
    const int lr = lane >> 3, ls = lane & 7;  // staging: row-in-group, seg
    const int sseg = ls ^ lr;                 // swizzled k-segment to fetch

    const u16* pa = hidb + (size_t)(row0 + wave * 32 + lr) * Dc + sseg * 8;
    const u16* pb = WT   + (size_t)(c0   + wave * 32 + lr) * Dc + sseg * 8;
    u16* la = &As[(wave * 32) * 64];
    u16* lb = &Bs[(wave * 32) * 64];

    f32x4 acc[4][4] = {};

    const int swz = (li & 7);                 // fragment-read swizzle key

    for (int kt = 0; kt < Dc; kt += 64) {
        __syncthreads();
#pragma unroll
        for (int i = 0; i < 4; ++i) {
            glds16(pa + kt + i * 8 * Dc, la + i * 8 * 64);
            glds16(pb + kt + i * 8 * Dc, lb + i * 8 * 64);
        }
        __syncthreads();
#pragma unroll
        for (int ks = 0; ks < 2; ++ks) {
            const int soff = ((ks * 4 + g) ^ swz) * 8;
            bf16x8 af[4], bf[4];
#pragma unroll
            for (int mi = 0; mi < 4; ++mi)
                af[mi] = *(const bf16x8*)&As[(wr * 64 + mi * 16 + li) * 64 + soff];
#pragma unroll
            for (int nj = 0; nj < 4; ++nj)
                bf[nj] = *(const bf16x8*)&Bs[(wc * 64 + nj * 16 + li) * 64 + soff];
#pragma unroll
            for (int mi = 0; mi < 4; ++mi)
#pragma unroll
                for (int nj = 0; nj < 4; ++nj)
                    acc[mi][nj] = __builtin_amdgcn_mfma_f32_16x16x32_bf16(
                        af[mi], bf[nj], acc[mi][nj], 0, 0, 0);
        }
    }

    const int b = row0 >> 10;

    if (z != 2) {
        // sigma-d epilogue: lane's 4 cols {li,li+16,li+32,li+48} -> sigma
        // positions 4*li..4*li+3 (contiguous): one b64 RTNE store per (mi,rr)
        const int h2 = (c0 + wc * 64) >> 6;
        const int nbase = (row0 & 1023) + wr * 64 + g * 4;
#pragma unroll
        for (int mi = 0; mi < 4; ++mi)
#pragma unroll
            for (int rr = 0; rr < 4; ++rr) {
                int n = nbase + mi * 16 + rr;
                u32x2 pk;
                pk.x = (u32)f2bf(acc[mi][0][rr]) | ((u32)f2bf(acc[mi][1][rr]) << 16);
                pk.y = (u32)f2bf(acc[mi][2][rr]) | ((u32)f2bf(acc[mi][3][rr]) << 16);
                *(u32x2*)(out + ((size_t)(b * Hc + h2) * Nc + n) * DHc + 4 * li) = pk;
            }
    } else {
        // per-wave 64x64 transpose in LDS scratch; key dim stored in
        // sigma-permuted order with the usual XOR seg swizzle.
        __syncthreads();
        u16* T = ((wave & 2) ? Bs : As) + (wave & 1) * 4096;
#pragma unroll
        for (int mi = 0; mi < 4; ++mi)
#pragma unroll
            for (int rr = 0; rr < 4; ++rr) {
                int r = mi * 16 + g * 4 + rr;
                int pp = ((r & 15) << 2) | (r >> 4);     // sigma(r)
#pragma unroll
                for (int nj = 0; nj < 4; ++nj) {
                    int c = nj * 16 + li;
                    T[c * 64 + ((((pp >> 3) ^ (c & 7)) << 3) | (pp & 7))]
                        = f2bf(acc[mi][nj][rr]);
                }
            }
        const int nseg = ls ^ lr;
#pragma unroll
        for (int i = 0; i < 8; ++i) {
            int cl = i * 8 + lr;              // local col (d)
            u16x8 val = *(const u16x8*)&T[cl * 64 + ls * 8];
            int cz = c0 + wc * 64 + cl;
            int n = (row0 & 1023) + wr * 64 + nseg * 8;
            *(u16x8*)&out[(((size_t)(b * Hc + (cz >> 6)) * DHc + (cz & 63)) * Nc) + n] = val;
        }
    }
}

// ---------------------------------------------------------------------------
// Kernel 2: flash attention v3 — double-buffered K/V staging, ONE barrier per
// K-tile. glds for tile i+1 + bias prefetch issue right after the barrier;
// the next barrier's vmcnt drain lands after a full compute phase (pipeline).
// 128-q tile, 4 waves (wave owns 32 q-rows). Fixed-max softmax (max==0 safe).
// q/k are sigma-permuted along d (consistent pair -> dot product unchanged);
// V pre-transposed [B,H,DH,N] with sigma key order; bias sigma-key-permuted.
// ---------------------------------------------------------------------------
__global__ __launch_bounds__(256, 3) void attn_mfma(
    const u16* __restrict__ q, const u16* __restrict__ k,
    const u16* __restrict__ v, const u16* __restrict__ bias,
    float* __restrict__ attn_out)
{
    __shared__ u16 Ks[2][64 * 64];    // [buf][key][kseg^(key&7)]
    __shared__ u16 VTs[2][64 * 64];   // [buf][d][pkseg^(d&7)]
    __shared__ u16 PQ[128 * 72];      // Q staging, then P tile [qrow][pkey]

    const int tid = threadIdx.x;
    const int w = tid >> 6, lane = tid & 63;
    const int g = lane >> 4, li = lane & 15;
    const int lr8 = lane >> 3, ls8 = lane & 7;
    const int lseg = ls8 ^ lr8;               // swizzled staging k-seg

    // XCD-locality remap: all 8 q-tiles of pair (b,h) share id%8
    const int id = blockIdx.x;
    const int p  = (id & 7) | ((id >> 6) << 3);   // 0..127 = b*16+h
    const int qt = (id >> 3) & 7;
    const int b = p >> 4, h = p & 15;
    const int q0 = qt << 7;

    const float scale = 0.03125f;  // 1/sqrt(1024)
    const u16* kbase = k + (size_t)(b * Hc + h) * Nc * DHc;
    const u16* vbase = v + (size_t)(b * Hc + h) * DHc * Nc;
    const u16* brow  = bias + ((size_t)(b * Nc) + q0 + w * 32) * Nc + 4 * li;

    // ---- prologue: issue tile-0 staging first (max overlap with Q setup) ----
    {
        const u16* kp = kbase + (size_t)(w * 16 + lr8) * DHc + lseg * 8;
        const u16* vp = vbase + (size_t)(w * 16 + lr8) * Nc + lseg * 8;
        glds16(kp,           &Ks[0][(w * 16) * 64]);
        glds16(kp + 8 * DHc, &Ks[0][(w * 16) * 64 + 8 * 64]);
        glds16(vp,           &VTs[0][(w * 16) * 64]);
        glds16(vp + 8 * Nc,  &VTs[0][(w * 16) * 64 + 8 * 64]);
    }

    // ---- stage Q [128][64] into PQ (wave-private rows: no barrier needed) ----
    {
        const int sr = tid >> 1;
        const int sh = (tid & 1) * 32;
        const u16* qp = q + ((size_t)((b * Hc + h) * Nc) + q0 + sr) * DHc + sh;
        u16x8 a0 = *(const u16x8*)qp;
        u16x8 a1 = *(const u16x8*)(qp + 8);
        u16x8 a2 = *(const u16x8*)(qp + 16);
        u16x8 a3 = *(const u16x8*)(qp + 24);
        u16* dst = &PQ[sr * 72 + sh];
        *(u16x8*)(dst)      = a0; *(u16x8*)(dst + 8)  = a1;
        *(u16x8*)(dst + 16) = a2; *(u16x8*)(dst + 24) = a3;
    }

    // bias tile 0 prefetch
    u16x4 brv[2][4];
#pragma unroll
    for (int mt = 0; mt < 2; ++mt)
#pragma unroll
        for (int r = 0; r < 4; ++r)
            brv[mt][r] = *(const u16x4*)&brow[(size_t)(mt * 16 + g * 4 + r) * Nc];

    // Q fragments (intra-wave LDS dependency only)
    bf16x8 qf[2][2];
#pragma unroll
    for (int mt = 0; mt < 2; ++mt)
#pragma unroll
        for (int ks = 0; ks < 2; ++ks)
            qf[mt][ks] = *(const bf16x8*)&PQ[(w * 32 + mt * 16 + li) * 72 + ks * 32 + g * 8];

    f32x4 o_[2][4] = {};
    float lsum[2][4] = {};

    for (int it = 0; it < 16; ++it) {
        const int cur = it & 1;
        __syncthreads();   // drains own glds/bias for tile it; syncs buffers

        u16x4 brn[2][4];
        if (it < 15) {     // issue tile it+1 staging into the other buffer
            const int k1 = (it + 1) * 64;
            const u16* kp = kbase + (size_t)(k1 + w * 16 + lr8) * DHc + lseg * 8;
            const u16* vp = vbase + (size_t)(w * 16 + lr8) * Nc + k1 + lseg * 8;
            u16* kl = &Ks[cur ^ 1][(w * 16) * 64];
            u16* vl = &VTs[cur ^ 1][(w * 16) * 64];
            glds16(kp,           kl);
            glds16(kp + 8 * DHc, kl + 8 * 64);
            glds16(vp,           vl);
            glds16(vp + 8 * Nc,  vl + 8 * 64);
#pragma unroll
            for (int mt = 0; mt < 2; ++mt)
#pragma unroll
                for (int r = 0; r < 4; ++r)
                    brn[mt][r] = *(const u16x4*)&brow[(size_t)(mt * 16 + g * 4 + r) * Nc + k1];
        }

        // --- S = Q.K^T : 16 MFMA, 8 K-frag b128 reads ---
        f32x4 sacc[2][4] = {};
#pragma unroll
        for (int ks = 0; ks < 2; ++ks) {
            const int so = (((ks << 2) | g) ^ (li & 7)) << 3;
#pragma unroll
            for (int nt = 0; nt < 4; ++nt) {
                bf16x8 kf = *(const bf16x8*)&Ks[cur][(nt * 16 + li) * 64 + so];
                sacc[0][nt] = __builtin_amdgcn_mfma_f32_16x16x32_bf16(qf[0][ks], kf, sacc[0][nt], 0, 0, 0);
                sacc[1][nt] = __builtin_amdgcn_mfma_f32_16x16x32_bf16(qf[1][ks], kf, sacc[1][nt], 0, 0, 0);
            }
        }

        // --- softmax from registers; P packed to b64 in sigma-space ---
#pragma unroll
        for (int mt = 0; mt < 2; ++mt)
#pragma unroll
            for (int r = 0; r < 4; ++r) {
                const int qrl = mt * 16 + g * 4 + r;
                float pv[4];
#pragma unroll
                for (int nt = 0; nt < 4; ++nt) {
                    float sv = sacc[mt][nt][r] * scale + bf2f(brv[mt][r][nt]);
                    pv[nt] = __expf(sv);
                    lsum[mt][r] += pv[nt];
                }
                u32* dst = (u32*)&PQ[(w * 32 + qrl) * 72 + li * 4];
                dst[0] = pack2bf(pv[0], pv[1]);
                dst[1] = pack2bf(pv[2], pv[3]);
            }

        // --- O += P.V : 16 MFMA, 4 P-frag + 8 VT-frag b128 reads ---
#pragma unroll
        for (int ks = 0; ks < 2; ++ks) {
            const int so = (((ks << 2) | g) ^ (li & 7)) << 3;
            bf16x8 pa0 = *(const bf16x8*)&PQ[(w * 32 + li) * 72 + ks * 32 + g * 8];
            bf16x8 pa1 = *(const bf16x8*)&PQ[(w * 32 + 16 + li) * 72 + ks * 32 + g * 8];
#pragma unroll
            for (int j = 0; j < 4; ++j) {
                bf16x8 vf = *(const bf16x8*)&VTs[cur][(j * 16 + li) * 64 + so];
                o_[0][j] = __builtin_amdgcn_mfma_f32_16x16x32_bf16(pa0, vf, o_[0][j], 0, 0, 0);
                o_[1][j] = __builtin_amdgcn_mfma_f32_16x16x32_bf16(pa1, vf, o_[1][j], 0, 0, 0);
            }
        }

        if (it < 15) {
#pragma unroll
            for (int mt = 0; mt < 2; ++mt)
#pragma unroll
                for (int r = 0; r < 4; ++r)
                    brv[mt][r] = brn[mt][r];
        }
    }

    // --- epilogue: reduce row sums across 16 li lanes, normalize, write ---
#pragma unroll
    for (int mt = 0; mt < 2; ++mt)
#pragma unroll
        for (int r = 0; r < 4; ++r) {
            float l = lsum[mt][r];
            l += __shfl_xor(l, 1);
            l += __shfl_xor(l, 2);
            l += __shfl_xor(l, 4);
            l += __shfl_xor(l, 8);
            float inv = 1.f / l;
            int qrow = q0 + w * 32 + mt * 16 + g * 4 + r;
            float* op = attn_out + ((size_t)b * Nc + qrow) * Dc + h * DHc;
#pragma unroll
            for (int j = 0; j < 4; ++j)
                op[j * 16 + li] = o_[mt][j][r] * inv;
        }
}

// ---------------------------------------------------------------------------
// Kernel 3: out = LayerNorm(relu(attn_out) + hid), in-place safe.
// ---------------------------------------------------------------------------
__global__ __launch_bounds__(256) void ln_kernel(
    const float* attn_out, const float* __restrict__ hid,
    const float* __restrict__ gamma, const float* __restrict__ beta,
    float* out)
{
    const int row = blockIdx.x;
    const int t = threadIdx.x;

    float4 av = *(const float4*)&attn_out[(size_t)row * Dc + t * 4];
    float4 hv = *(const float4*)&hid[(size_t)row * Dc + t * 4];
    float x0 = fmaxf(av.x, 0.f) + hv.x;
    float x1 = fmaxf(av.y, 0.f) + hv.y;
    float x2 = fmaxf(av.z, 0.f) + hv.z;
    float x3 = fmaxf(av.w, 0.f) + hv.w;

    float s1 = x0 + x1 + x2 + x3;
    float s2 = x0 * x0 + x1 * x1 + x2 * x2 + x3 * x3;
#pragma unroll
    for (int off = 1; off < 64; off <<= 1) {
        s1 += __shfl_xor(s1, off);
        s2 += __shfl_xor(s2, off);
    }
    __shared__ float w1[4], w2[4];
    int lane = t & 63, wid = t >> 6;
    if (lane == 0) { w1[wid] = s1; w2[wid] = s2; }
    __syncthreads();
    s1 = w1[0] + w1[1] + w1[2] + w1[3];
    s2 = w2[0] + w2[1] + w2[2] + w2[3];

    float mu  = s1 * (1.f / 1024.f);
    float var = s2 * (1.f / 1024.f) - mu * mu;
    float rstd = rsqrtf(var + 1e-5f);

    float4 g  = *(const float4*)&gamma[t * 4];
    float4 be = *(const float4*)&beta[t * 4];
    float4 r4;
    r4.x = (x0 - mu) * rstd * g.x + be.x;
    r4.y = (x1 - mu) * rstd * g.y + be.y;
    r4.z = (x2 - mu) * rstd * g.z + be.z;
    r4.w = (x3 - mu) * rstd * g.w + be.w;
    *(float4*)&out[(size_t)row * Dc + t * 4] = r4;
}

extern "C" void kernel_launch(void* const* d_in, const int* in_sizes, int n_in,
                              void* d_out, int out_size, void* d_ws, size_t ws_size,
                              hipStream_t stream) {
    const float* hid       = (const float*)d_in[0];
    const int*   adj       = (const int*)d_in[1];
    const int*   relpos    = (const int*)d_in[2];
    const float* Wq        = (const float*)d_in[3];
    const float* Wk        = (const float*)d_in[4];
    const float* Wv        = (const float*)d_in[5];
    const float* rel_table = (const float*)d_in[6];
    const float* gamma     = (const float*)d_in[7];
    const float* beta      = (const float*)d_in[8];
    float* out = (float*)d_out;

    const size_t per  = (size_t)Bc * Hc * Nc * DHc;  // 8,388,608
    const size_t wsz  = (size_t)Dc * Dc;             // 1,048,576
    u16* qb   = (u16*)d_ws;                // sigma-d
    u16* kb   = qb + per;                  // sigma-d
    u16* vb   = kb + per;                  // [B,H,DH,N] transposed+sigma-key
    u16* bias = vb + per;                  // B*N*N sigma-key-permuted
    u16* hidb = bias + (size_t)Bc * Nc * Nc;
    u16* wqT  = hidb + (size_t)Bc * Nc * Dc;
    u16* wkT  = wqT + wsz;
    u16* wvT  = wkT + wsz;
    // total ws: ~90.2 MB

    prep_fused<<<15360, 256, 0, stream>>>(adj, relpos, rel_table, bias,
                                          hid, hidb, Wq, Wk, Wv, wqT, wkT, wvT);
    qkv_mfma<<<dim3(24, 64), 256, 0, stream>>>(hidb, wqT, wkT, wvT, qb, kb, vb);
    attn_mfma<<<1024, 256, 0, stream>>>(qb, kb, vb, bias, out);
    ln_kernel<<<Bc * Nc, 256, 0, stream>>>(out, hid, gamma, beta, out);
}